// Round 11
// baseline (236.431 us; speedup 1.0000x reference)
//
#include <hip/hip_runtime.h>

#define N_NODES 100000
#define N_EDGES 640000
#define D       128
#define NT      ((N_NODES + 127) / 128)    // 782 row-tiles for gemm
#define SLOTS   16
#define SPILL_CAP 65536

// ---- PATH A2 ws layout (4B words), needs ~33.0 MB ------------------------
#define A2_XB    0          // bf16 [12800000] = 6,400,000 words (x in bf16)
#define A2_CNT   6400000    // int  [100001] (last = spill counter)
#define A2_COL   6500002    // int  [1600000]
#define A2_SPILL 8100002    // int2 [65536] (even word -> 8B aligned)
#define A2_BIAS  8231074    // f32  [128]
#define A2_WT    8231204    // bf16 [32768] = 16384 words (word%4==0 -> 16B aligned)
#define A2_TOTAL 8247588    // words = 32.99 MB

// ---- PATH A ws layout (round-8 verified fallback), ~7.39 MB --------------
#define A_CNT   0
#define A_COL   100002
#define A_SPILL 1700002
#define A_BIAS  1831074
#define A_WT    1831204
#define A_TOTAL 1847588

// RNE float->bf16 (finite inputs only)
__device__ __forceinline__ unsigned short f2bf(float f) {
    union { float f; unsigned u; } c; c.f = f;
    unsigned r = c.u + 0x7fffu + ((c.u >> 16) & 1u);
    return (unsigned short)(r >> 16);
}
__device__ __forceinline__ unsigned pack2bf(float a, float b) {
    return (unsigned)f2bf(a) | ((unsigned)f2bf(b) << 16);
}
__device__ __forceinline__ float bflo(unsigned v) {
    union { unsigned u; float f; } c; c.u = (v & 0xffffu) << 16; return c.f;
}
__device__ __forceinline__ float bfhi(unsigned v) {
    union { unsigned u; float f; } c; c.u = v & 0xffff0000u; return c.f;
}

// ===========================================================================
// PATH A2 prep: W swizzle + bias + cnt zero + xcast (x fp32 -> bf16)
// Wt content: Wt[n][k] = Wcat[k][n], Wcat = [W_self ; W_neigh] (256 x 128).
// Global byte n*512 + (((k>>3) ^ (n&15))*16) + (k&7)*2 holds Wcat[k][n]
// (rule #21: swizzled source + swizzled read, linear LDS copy).
// grid 6250 x 256 = 1.6M threads (exact for xcast: 12.8M floats / 8)
// ===========================================================================
__global__ __launch_bounds__(256) void k_prep2(
    const float* __restrict__ Wself, const float* __restrict__ Wneigh,
    const float* __restrict__ bself, const float* __restrict__ bneigh,
    const float* __restrict__ x,
    unsigned short* wt, float* bias, int* cnt, unsigned short* xb)
{
    int i = blockIdx.x * 256 + threadIdx.x;
    {   // xcast: 8 floats -> 8 bf16 (16B store)
        const float4* xf4 = (const float4*)x;
        float4 v0 = xf4[(size_t)i * 2];
        float4 v1 = xf4[(size_t)i * 2 + 1];
        uint4 p;
        p.x = pack2bf(v0.x, v0.y);
        p.y = pack2bf(v0.z, v0.w);
        p.z = pack2bf(v1.x, v1.y);
        p.w = pack2bf(v1.z, v1.w);
        ((uint4*)xb)[i] = p;
    }
    if (i < 32768) {
        int k = i >> 7, n = i & 127;
        float v = (k < 128) ? Wself[k * 128 + n] : Wneigh[(k - 128) * 128 + n];
        int byte = n * 512 + (((k >> 3) ^ (n & 15)) << 4) + ((k & 7) << 1);
        *(unsigned short*)((char*)wt + byte) = f2bf(v);
    }
    if (i < N_NODES + 1) cnt[i] = 0;
    if (blockIdx.x == 0 && threadIdx.x < 128)
        bias[threadIdx.x] = bself[threadIdx.x] + bneigh[threadIdx.x];
}

// ---------------------------------------------------------------------------
// adjacency build: fixed 16 slots + spill pool (round-8 verified)
// ---------------------------------------------------------------------------
__global__ __launch_bounds__(256) void k_scat16(
    const int* __restrict__ ei, int* cnt, int* col16, int2* spill)
{
    int e = blockIdx.x * 256 + threadIdx.x;
    int src = ei[e];
    int dst = ei[N_EDGES + e];
    int pos = atomicAdd(&cnt[dst], 1);       // histogram AND cursor
    if (pos < SLOTS) {
        col16[dst * SLOTS + pos] = src;
    } else {
        int j = atomicAdd(&cnt[N_NODES], 1);
        if (j < SPILL_CAP) spill[j] = make_int2(dst, src);
    }
}

// ---------------------------------------------------------------------------
// A2 gather: mean from bf16 x-rows (256B each); mean stored as bf16 packed
// into the FIRST 256B of each d_out row (block-local for gemm's in-place
// read). One wave per node, lane l covers features 2l, 2l+1.
// ---------------------------------------------------------------------------
__global__ __launch_bounds__(256) void k_gather16b(
    const unsigned* __restrict__ xbu, const int* __restrict__ cnt,
    const int* __restrict__ col16, const int2* __restrict__ spill,
    float* out)
{
    int node = blockIdx.x * 4 + (threadIdx.x >> 6);      // grid 25000 exact
    int l = threadIdx.x & 63;
    int deg = cnt[node];
    int m = min(deg, SLOTS);
    int c = (l < m) ? col16[node * SLOTS + l] : 0;

    float2 acc = make_float2(0.f, 0.f);
    int j = 0;
    for (; j + 2 <= m; j += 2) {
        int s0 = __shfl(c, j);
        int s1 = __shfl(c, j + 1);
        unsigned v0 = xbu[(size_t)s0 * 64 + l];          // 64 uints per row
        unsigned v1 = xbu[(size_t)s1 * 64 + l];
        acc.x += bflo(v0) + bflo(v1);
        acc.y += bfhi(v0) + bfhi(v1);
    }
    if (j < m) {
        int s0 = __shfl(c, j);
        unsigned v0 = xbu[(size_t)s0 * 64 + l];
        acc.x += bflo(v0);
        acc.y += bfhi(v0);
    }
    if (deg > SLOTS) {                        // rare: scan spill pool
        int tot = min(cnt[N_NODES], SPILL_CAP);
        for (int i = 0; i < tot; ++i) {
            int2 p = spill[i];
            if (p.x == node) {
                unsigned v0 = xbu[(size_t)p.y * 64 + l];
                acc.x += bflo(v0);
                acc.y += bfhi(v0);
            }
        }
    }
    float inv = 1.0f / fmaxf((float)deg, 1.0f);
    ((unsigned*)out)[(size_t)node * 128 + l] = pack2bf(acc.x * inv, acc.y * inv);
}

// ===========================================================================
// A2 GEMM: out[r] = [x[r] | mean[r]] @ Wcat + bias  (all-bf16 staging)
// A-tile LDS [128 rows][512B], 16B units, XOR swizzle unit ^= (r&15).
// x-half from xb (256B/row); mean-half from d_out row's first 256B (bf16).
// MFMA core + epilogue identical to round-8 verified kernel.
// ===========================================================================
typedef __attribute__((ext_vector_type(8))) short bf16x8;
typedef __attribute__((ext_vector_type(4))) float f32x4;

extern __shared__ char ldsb[];

__global__ __launch_bounds__(256) void k_gemm2(
    const unsigned short* __restrict__ xb,
    const unsigned short* __restrict__ wt,
    const float* __restrict__ bias,
    float* __restrict__ outp)
{
    char* ldsA = ldsb;               // 65536 B
    char* ldsW = ldsb + 65536;       // 65536 B

    const int w = threadIdx.x >> 6, l = threadIdx.x & 63;
    const int r0 = blockIdx.x * 128;

    {   // stage W: linear 16B copies (content already swizzled)
        const uint4* wt4 = (const uint4*)wt;          // 4096 x 16B
        #pragma unroll
        for (int it = 0; it < 16; ++it) {
            int q = (w * 16 + it) * 64 + l;
            *(uint4*)(ldsW + (size_t)q * 16) = wt4[q];
        }
    }

    // stage A x-half: per pass 4 rows x 16 units; 8 passes for 32 rows/wave
    {
        const int u = l & 15, rs = l >> 4;            // unit, row-sub
        uint4 v[8];
        #pragma unroll
        for (int it = 0; it < 8; ++it) {
            int rloc = w * 32 + it * 4 + rs;
            int rg   = min(r0 + rloc, N_NODES - 1);
            v[it] = ((const uint4*)xb)[(size_t)rg * 16 + u];
        }
        #pragma unroll
        for (int it = 0; it < 8; ++it) {
            int rloc = w * 32 + it * 4 + rs;
            *(uint4*)(ldsA + rloc * 512 + ((u ^ (rloc & 15)) << 4)) = v[it];
        }
    }
    // stage A mean-half: bf16 packed in first 256B of each out row
    {
        const int u = l & 15, rs = l >> 4;
        uint4 v[8];
        #pragma unroll
        for (int it = 0; it < 8; ++it) {
            int rloc = w * 32 + it * 4 + rs;
            int rg   = min(r0 + rloc, N_NODES - 1);
            v[it] = *(const uint4*)((const char*)outp + (size_t)rg * 512 + u * 16);
        }
        #pragma unroll
        for (int it = 0; it < 8; ++it) {
            int rloc = w * 32 + it * 4 + rs;
            *(uint4*)(ldsA + rloc * 512 + (((16 + u) ^ (rloc & 15)) << 4)) = v[it];
        }
    }
    __syncthreads();

    const int ln = l & 15, kq = l >> 4;
    const int rA0 = w * 32 + ln;
    const int rA1 = rA0 + 16;

    f32x4 acc[2][8];
    #pragma unroll
    for (int rg = 0; rg < 2; ++rg)
        #pragma unroll
        for (int cg = 0; cg < 8; ++cg)
            acc[rg][cg] = (f32x4){0.f, 0.f, 0.f, 0.f};

    #pragma unroll
    for (int ks = 0; ks < 8; ++ks) {
        int i = ks * 4 + kq;
        bf16x8 a0 = *(const bf16x8*)(ldsA + rA0 * 512 + ((i ^ ln) << 4));
        bf16x8 a1 = *(const bf16x8*)(ldsA + rA1 * 512 + ((i ^ ln) << 4));
        #pragma unroll
        for (int cg = 0; cg < 8; ++cg) {
            int n = cg * 16 + ln;
            bf16x8 bfr = *(const bf16x8*)(ldsW + n * 512 + ((i ^ ln) << 4));
            acc[0][cg] = __builtin_amdgcn_mfma_f32_16x16x32_bf16(a0, bfr, acc[0][cg], 0, 0, 0);
            acc[1][cg] = __builtin_amdgcn_mfma_f32_16x16x32_bf16(a1, bfr, acc[1][cg], 0, 0, 0);
        }
    }

    float bv[8];
    #pragma unroll
    for (int cg = 0; cg < 8; ++cg) bv[cg] = bias[cg * 16 + ln];

    #pragma unroll
    for (int rg = 0; rg < 2; ++rg) {
        int rbase = r0 + w * 32 + rg * 16 + kq * 4;
        #pragma unroll
        for (int q = 0; q < 4; ++q) {
            int rr = rbase + q;
            if (rr < N_NODES) {
                float* op = outp + (size_t)rr * D + ln;
                #pragma unroll
                for (int cg = 0; cg < 8; ++cg)
                    op[cg * 16] = acc[rg][cg][q] + bv[cg];
            }
        }
    }
}

// ===========================================================================
// PATH A fallback (round-8 verified): fp32 gather + f2bf-staging gemm
// ===========================================================================
__global__ __launch_bounds__(256) void k_prepw(
    const float* __restrict__ Wself, const float* __restrict__ Wneigh,
    const float* __restrict__ bself, const float* __restrict__ bneigh,
    unsigned short* wt, float* bias, int* cnt, int n_zero)
{
    int i = blockIdx.x * 256 + threadIdx.x;
    if (i < 32768) {
        int k = i >> 7, n = i & 127;
        float v = (k < 128) ? Wself[k * 128 + n] : Wneigh[(k - 128) * 128 + n];
        int byte = n * 512 + (((k >> 3) ^ (n & 15)) << 4) + ((k & 7) << 1);
        *(unsigned short*)((char*)wt + byte) = f2bf(v);
    }
    if (i < n_zero) cnt[i] = 0;
    if (blockIdx.x == 0 && threadIdx.x < 128)
        bias[threadIdx.x] = bself[threadIdx.x] + bneigh[threadIdx.x];
}

__global__ __launch_bounds__(256) void k_gather16(
    const float* __restrict__ x, const int* __restrict__ cnt,
    const int* __restrict__ col16, const int2* __restrict__ spill,
    float* out)
{
    int node = blockIdx.x * 4 + (threadIdx.x >> 6);
    int l = threadIdx.x & 63;
    int deg = cnt[node];
    int m = min(deg, SLOTS);
    int c = (l < m) ? col16[node * SLOTS + l] : 0;

    float2 acc = make_float2(0.f, 0.f);
    int j = 0;
    for (; j + 2 <= m; j += 2) {
        int s0 = __shfl(c, j);
        int s1 = __shfl(c, j + 1);
        float2 a = ((const float2*)(x + (size_t)s0 * D))[l];
        float2 b = ((const float2*)(x + (size_t)s1 * D))[l];
        acc.x += a.x + b.x;
        acc.y += a.y + b.y;
    }
    if (j < m) {
        int s0 = __shfl(c, j);
        float2 a = ((const float2*)(x + (size_t)s0 * D))[l];
        acc.x += a.x;
        acc.y += a.y;
    }
    if (deg > SLOTS) {
        int tot = min(cnt[N_NODES], SPILL_CAP);
        for (int i = 0; i < tot; ++i) {
            int2 p = spill[i];
            if (p.x == node) {
                float2 a = ((const float2*)(x + (size_t)p.y * D))[l];
                acc.x += a.x;
                acc.y += a.y;
            }
        }
    }
    float inv = 1.0f / fmaxf((float)deg, 1.0f);
    ((float2*)(out + (size_t)node * D))[l] = make_float2(acc.x * inv, acc.y * inv);
}

__global__ __launch_bounds__(256) void k_gemm(
    const float* __restrict__ x,
    const unsigned short* __restrict__ wt,
    const float* __restrict__ bias,
    float* outp)
{
    char* ldsA = ldsb;
    char* ldsW = ldsb + 65536;

    const int w = threadIdx.x >> 6, l = threadIdx.x & 63;
    const int r0 = blockIdx.x * 128;

    {
        const uint4* wt4 = (const uint4*)wt;
        #pragma unroll
        for (int it = 0; it < 16; ++it) {
            int q = (w * 16 + it) * 64 + l;
            *(uint4*)(ldsW + (size_t)q * 16) = wt4[q];
        }
    }
    {
        const float4* xf = (const float4*)x;
        const float4* mf = (const float4*)outp;
        float4 vx[16], vm[16];
        #pragma unroll
        for (int it = 0; it < 16; ++it) {
            int rl = 2 * it + (l >> 5);
            int rg = min(r0 + w * 32 + rl, N_NODES - 1);
            int j  = l & 31;
            vx[it] = xf[(size_t)rg * 32 + j];
            vm[it] = mf[(size_t)rg * 32 + j];
        }
        #pragma unroll
        for (int it = 0; it < 16; ++it) {
            int rloc = w * 32 + 2 * it + (l >> 5);
            int j    = l & 31;
            {
                int unit = ((j >> 1) ^ (rloc & 15));
                ushort4 b;
                b.x = f2bf(vx[it].x); b.y = f2bf(vx[it].y);
                b.z = f2bf(vx[it].z); b.w = f2bf(vx[it].w);
                *(ushort4*)(ldsA + rloc * 512 + (unit << 4) + ((j & 1) << 3)) = b;
            }
            {
                int unit = ((16 + (j >> 1)) ^ (rloc & 15));
                ushort4 b;
                b.x = f2bf(vm[it].x); b.y = f2bf(vm[it].y);
                b.z = f2bf(vm[it].z); b.w = f2bf(vm[it].w);
                *(ushort4*)(ldsA + rloc * 512 + (unit << 4) + ((j & 1) << 3)) = b;
            }
        }
    }
    __syncthreads();

    const int ln = l & 15, kq = l >> 4;
    const int rA0 = w * 32 + ln;
    const int rA1 = rA0 + 16;

    f32x4 acc[2][8];
    #pragma unroll
    for (int rg = 0; rg < 2; ++rg)
        #pragma unroll
        for (int cg = 0; cg < 8; ++cg)
            acc[rg][cg] = (f32x4){0.f, 0.f, 0.f, 0.f};

    #pragma unroll
    for (int ks = 0; ks < 8; ++ks) {
        int i = ks * 4 + kq;
        bf16x8 a0 = *(const bf16x8*)(ldsA + rA0 * 512 + ((i ^ ln) << 4));
        bf16x8 a1 = *(const bf16x8*)(ldsA + rA1 * 512 + ((i ^ ln) << 4));
        #pragma unroll
        for (int cg = 0; cg < 8; ++cg) {
            int n = cg * 16 + ln;
            bf16x8 bfr = *(const bf16x8*)(ldsW + n * 512 + ((i ^ ln) << 4));
            acc[0][cg] = __builtin_amdgcn_mfma_f32_16x16x32_bf16(a0, bfr, acc[0][cg], 0, 0, 0);
            acc[1][cg] = __builtin_amdgcn_mfma_f32_16x16x32_bf16(a1, bfr, acc[1][cg], 0, 0, 0);
        }
    }

    float bv[8];
    #pragma unroll
    for (int cg = 0; cg < 8; ++cg) bv[cg] = bias[cg * 16 + ln];

    #pragma unroll
    for (int rg = 0; rg < 2; ++rg) {
        int rbase = r0 + w * 32 + rg * 16 + kq * 4;
        #pragma unroll
        for (int q = 0; q < 4; ++q) {
            int rr = rbase + q;
            if (rr < N_NODES) {
                float* op = outp + (size_t)rr * D + ln;
                #pragma unroll
                for (int cg = 0; cg < 8; ++cg)
                    op[cg * 16] = acc[rg][cg][q] + bv[cg];
            }
        }
    }
}

// ---------------------------------------------------------------------------
extern "C" void kernel_launch(void* const* d_in, const int* in_sizes, int n_in,
                              void* d_out, int out_size, void* d_ws, size_t ws_size,
                              hipStream_t stream) {
    const float* x      = (const float*)d_in[0];
    const int*   ei     = (const int*)  d_in[1];
    const float* Wself  = (const float*)d_in[2];
    const float* bself  = (const float*)d_in[3];
    const float* Wneigh = (const float*)d_in[4];
    const float* bneigh = (const float*)d_in[5];

    float* out = (float*)d_out;
    int*   ws  = (int*)d_ws;
    size_t lds_bytes = 131072;

    if (ws_size >= (size_t)A2_TOTAL * 4 + 65536) {
        // ---- PATH A2: bf16 gather/staging, 4 dispatches ----
        unsigned short* xb  = (unsigned short*)(ws + A2_XB);
        int*  cnt   = ws + A2_CNT;
        int*  col16 = ws + A2_COL;
        int2* spill = (int2*)(ws + A2_SPILL);
        float* bias = (float*)(ws + A2_BIAS);
        unsigned short* wt = (unsigned short*)(ws + A2_WT);

        hipFuncSetAttribute((const void*)k_gemm2,
                            hipFuncAttributeMaxDynamicSharedMemorySize, (int)lds_bytes);
        k_prep2   <<<6250, 256, 0, stream>>>(Wself, Wneigh, bself, bneigh, x,
                                             wt, bias, cnt, xb);
        k_scat16  <<<N_EDGES / 256, 256, 0, stream>>>(ei, cnt, col16, spill);
        k_gather16b<<<N_NODES / 4, 256, 0, stream>>>((const unsigned*)xb, cnt,
                                                     col16, spill, out);
        k_gemm2   <<<NT, 256, lds_bytes, stream>>>(xb, wt, bias, out);
    } else {
        // ---- PATH A: round-8 verified fp32 path ----
        int*  cnt   = ws + A_CNT;
        int*  col16 = ws + A_COL;
        int2* spill = (int2*)(ws + A_SPILL);
        float* bias = (float*)(ws + A_BIAS);
        unsigned short* wt = (unsigned short*)(ws + A_WT);

        hipFuncSetAttribute((const void*)k_gemm,
                            hipFuncAttributeMaxDynamicSharedMemorySize, (int)lds_bytes);
        k_prepw   <<<391, 256, 0, stream>>>(Wself, Wneigh, bself, bneigh,
                                            wt, bias, cnt, N_NODES + 1);
        k_scat16  <<<N_EDGES / 256, 256, 0, stream>>>(ei, cnt, col16, spill);
        k_gather16<<<N_NODES / 4, 256, 0, stream>>>(x, cnt, col16, spill, out);
        k_gemm    <<<NT, 256, lds_bytes, stream>>>(x, wt, bias, out);
    }
}

// Round 14
// 206.889 us; speedup vs baseline: 1.1428x; 1.1428x over previous
//
#include <hip/hip_runtime.h>

#define N_NODES 100000
#define N_EDGES 640000
#define D       128
#define NT3     ((N_NODES + 255) / 256)    // 391 row-tiles for gemm3
#define SLOTS   16
#define SPILL_CAP 65536

// ---- ws layout (4B words), ~33.0 MB (round-11 proven available) ----------
#define A2_XB    0          // bf16 [12800000] = 6,400,000 words (x in bf16)
#define A2_CNT   6400000    // int  [100001] (last = spill counter)
#define A2_COL   6500002    // int  [1600000]
#define A2_SPILL 8100002    // int2 [65536] (even word -> 8B aligned)
#define A2_BIAS  8231074    // f32  [128]
#define A2_WT    8231204    // bf16 [32768] = 16384 words (word%4==0 -> 16B aligned)

// RNE float->bf16 (finite inputs only)
__device__ __forceinline__ unsigned short f2bf(float f) {
    union { float f; unsigned u; } c; c.f = f;
    unsigned r = c.u + 0x7fffu + ((c.u >> 16) & 1u);
    return (unsigned short)(r >> 16);
}
__device__ __forceinline__ unsigned pack2bf(float a, float b) {
    return (unsigned)f2bf(a) | ((unsigned)f2bf(b) << 16);
}
__device__ __forceinline__ float bflo(unsigned v) {
    union { unsigned u; float f; } c; c.u = (v & 0xffffu) << 16; return c.f;
}
__device__ __forceinline__ float bfhi(unsigned v) {
    union { unsigned u; float f; } c; c.u = v & 0xffff0000u; return c.f;
}

// ===========================================================================
// prep: W swizzle + bias + cnt zero + xcast (x fp32 -> bf16)
// Wt content: Wt[n][k] = Wcat[k][n], Wcat = [W_self ; W_neigh] (256 x 128).
// Global byte n*512 + (((k>>3) ^ (n&15))*16) + (k&7)*2 holds Wcat[k][n]
// (rule #21: swizzled source + swizzled read, linear LDS copy).
// ===========================================================================
__global__ __launch_bounds__(256) void k_prep2(
    const float* __restrict__ Wself, const float* __restrict__ Wneigh,
    const float* __restrict__ bself, const float* __restrict__ bneigh,
    const float* __restrict__ x,
    unsigned short* wt, float* bias, int* cnt, unsigned short* xb)
{
    int i = blockIdx.x * 256 + threadIdx.x;
    {   // xcast: 8 floats -> 8 bf16 (16B store); grid 6250*256*8 = 12.8M exact
        const float4* xf4 = (const float4*)x;
        float4 v0 = xf4[(size_t)i * 2];
        float4 v1 = xf4[(size_t)i * 2 + 1];
        uint4 p;
        p.x = pack2bf(v0.x, v0.y);
        p.y = pack2bf(v0.z, v0.w);
        p.z = pack2bf(v1.x, v1.y);
        p.w = pack2bf(v1.z, v1.w);
        ((uint4*)xb)[i] = p;
    }
    if (i < 32768) {
        int k = i >> 7, n = i & 127;
        float v = (k < 128) ? Wself[k * 128 + n] : Wneigh[(k - 128) * 128 + n];
        int byte = n * 512 + (((k >> 3) ^ (n & 15)) << 4) + ((k & 7) << 1);
        *(unsigned short*)((char*)wt + byte) = f2bf(v);
    }
    if (i < N_NODES + 1) cnt[i] = 0;
    if (blockIdx.x == 0 && threadIdx.x < 128)
        bias[threadIdx.x] = bself[threadIdx.x] + bneigh[threadIdx.x];
}

// ---------------------------------------------------------------------------
// adjacency build: fixed 16 slots + spill pool (round-8 verified)
// ---------------------------------------------------------------------------
__global__ __launch_bounds__(256) void k_scat16(
    const int* __restrict__ ei, int* cnt, int* col16, int2* spill)
{
    int e = blockIdx.x * 256 + threadIdx.x;
    int src = ei[e];
    int dst = ei[N_EDGES + e];
    int pos = atomicAdd(&cnt[dst], 1);       // histogram AND cursor
    if (pos < SLOTS) {
        col16[dst * SLOTS + pos] = src;
    } else {
        int j = atomicAdd(&cnt[N_NODES], 1);
        if (j < SPILL_CAP) spill[j] = make_int2(dst, src);
    }
}

// ---------------------------------------------------------------------------
// gather: mean from bf16 x-rows; result bf16-packed into the FIRST 256B of
// each d_out row (round-11 verified; <54us)
// ---------------------------------------------------------------------------
__global__ __launch_bounds__(256) void k_gather16b(
    const unsigned* __restrict__ xbu, const int* __restrict__ cnt,
    const int* __restrict__ col16, const int2* __restrict__ spill,
    float* out)
{
    int node = blockIdx.x * 4 + (threadIdx.x >> 6);      // grid 25000 exact
    int l = threadIdx.x & 63;
    int deg = cnt[node];
    int m = min(deg, SLOTS);
    int c = (l < m) ? col16[node * SLOTS + l] : 0;

    float2 acc = make_float2(0.f, 0.f);
    int j = 0;
    for (; j + 2 <= m; j += 2) {
        int s0 = __shfl(c, j);
        int s1 = __shfl(c, j + 1);
        unsigned v0 = xbu[(size_t)s0 * 64 + l];          // 64 uints per row
        unsigned v1 = xbu[(size_t)s1 * 64 + l];
        acc.x += bflo(v0) + bflo(v1);
        acc.y += bfhi(v0) + bfhi(v1);
    }
    if (j < m) {
        int s0 = __shfl(c, j);
        unsigned v0 = xbu[(size_t)s0 * 64 + l];
        acc.x += bflo(v0);
        acc.y += bfhi(v0);
    }
    if (deg > SLOTS) {                        // rare: scan spill pool
        int tot = min(cnt[N_NODES], SPILL_CAP);
        for (int i = 0; i < tot; ++i) {
            int2 p = spill[i];
            if (p.x == node) {
                unsigned v0 = xbu[(size_t)p.y * 64 + l];
                acc.x += bflo(v0);
                acc.y += bfhi(v0);
            }
        }
    }
    float inv = 1.0f / fmaxf((float)deg, 1.0f);
    ((unsigned*)out)[(size_t)node * 128 + l] = pack2bf(acc.x * inv, acc.y * inv);
}

// ===========================================================================
// GEMM3: out[r] = [x[r] | mean[r]] @ Wcat + bias — NO LDS FOR A.
// Latency fix for round-11's k_gemm2 (54us @ 7.3% occupancy):
//  - A-fragment = 16B contiguous per lane -> direct global load from xb
//    (ks<4) / d_out bf16-mean prefix (ks>=4); half select is compile-time.
//  - LDS = W only (64KB) -> 2 blocks/CU; 8 waves x 32 rows = 256-row tile
//    -> W staged half as often; no A-stage, no second barrier.
//  - each wave reads & writes only its own 32-row slice -> in-place mean
//    read is race-free across waves without extra sync.
// ===========================================================================
typedef __attribute__((ext_vector_type(8))) short bf16x8;
typedef __attribute__((ext_vector_type(4))) float f32x4;

extern __shared__ char ldsb[];

__global__ __launch_bounds__(512) void k_gemm3(
    const unsigned short* __restrict__ xb,
    const unsigned short* __restrict__ wt,
    const float* __restrict__ bias,
    float* __restrict__ outp)
{
    char* ldsW = ldsb;                        // 65536 B
    const int w = threadIdx.x >> 6, l = threadIdx.x & 63;
    const int r0 = blockIdx.x * 256;

    {   // stage W: 512 threads x 8 x 16B = 64KB (content pre-swizzled)
        const uint4* wt4 = (const uint4*)wt;  // 4096 x 16B
        #pragma unroll
        for (int it = 0; it < 8; ++it) {
            int q = it * 512 + (int)threadIdx.x;
            *(uint4*)(ldsW + (size_t)q * 16) = wt4[q];
        }
    }
    __syncthreads();

    const int ln = l & 15, kq = l >> 4;
    const int ra0 = min(r0 + w * 32 + ln,      N_NODES - 1);   // tail clamp:
    const int ra1 = min(r0 + w * 32 + 16 + ln, N_NODES - 1);   // own-block row

    f32x4 acc[2][8];
    #pragma unroll
    for (int rg = 0; rg < 2; ++rg)
        #pragma unroll
        for (int cg = 0; cg < 8; ++cg)
            acc[rg][cg] = (f32x4){0.f, 0.f, 0.f, 0.f};

    #pragma unroll
    for (int ks = 0; ks < 8; ++ks) {
        int i = ks * 4 + kq;                  // logical 16B unit 0..31
        bf16x8 a0, a1;
        if (ks < 4) {                         // x half: xb rows (256B each)
            a0 = *(const bf16x8*)((const char*)xb + (size_t)ra0 * 256 + (size_t)i * 16);
            a1 = *(const bf16x8*)((const char*)xb + (size_t)ra1 * 256 + (size_t)i * 16);
        } else {                              // mean half: out-row 256B prefix
            a0 = *(const bf16x8*)((const char*)outp + (size_t)ra0 * 512 + (size_t)(i - 16) * 16);
            a1 = *(const bf16x8*)((const char*)outp + (size_t)ra1 * 512 + (size_t)(i - 16) * 16);
        }
        #pragma unroll
        for (int cg = 0; cg < 8; ++cg) {
            int n = cg * 16 + ln;
            bf16x8 bfr = *(const bf16x8*)(ldsW + n * 512 + ((i ^ ln) << 4));
            acc[0][cg] = __builtin_amdgcn_mfma_f32_16x16x32_bf16(a0, bfr, acc[0][cg], 0, 0, 0);
            acc[1][cg] = __builtin_amdgcn_mfma_f32_16x16x32_bf16(a1, bfr, acc[1][cg], 0, 0, 0);
        }
    }

    // epilogue: C/D layout col=ln, row=kq*4+q (m89-verified)
    float bv[8];
    #pragma unroll
    for (int cg = 0; cg < 8; ++cg) bv[cg] = bias[cg * 16 + ln];

    #pragma unroll
    for (int rg = 0; rg < 2; ++rg) {
        int rbase = r0 + w * 32 + rg * 16 + kq * 4;
        #pragma unroll
        for (int q = 0; q < 4; ++q) {
            int rr = rbase + q;
            if (rr < N_NODES) {
                float* op = outp + (size_t)rr * D + ln;
                #pragma unroll
                for (int cg = 0; cg < 8; ++cg)
                    op[cg * 16] = acc[rg][cg][q] + bv[cg];
            }
        }
    }
}

// ---------------------------------------------------------------------------
extern "C" void kernel_launch(void* const* d_in, const int* in_sizes, int n_in,
                              void* d_out, int out_size, void* d_ws, size_t ws_size,
                              hipStream_t stream) {
    const float* x      = (const float*)d_in[0];
    const int*   ei     = (const int*)  d_in[1];
    const float* Wself  = (const float*)d_in[2];
    const float* bself  = (const float*)d_in[3];
    const float* Wneigh = (const float*)d_in[4];
    const float* bneigh = (const float*)d_in[5];

    float* out = (float*)d_out;
    int*   ws  = (int*)d_ws;

    unsigned short* xb  = (unsigned short*)(ws + A2_XB);
    int*  cnt   = ws + A2_CNT;
    int*  col16 = ws + A2_COL;
    int2* spill = (int2*)(ws + A2_SPILL);
    float* bias = (float*)(ws + A2_BIAS);
    unsigned short* wt = (unsigned short*)(ws + A2_WT);

    size_t lds_bytes = 65536;
    hipFuncSetAttribute((const void*)k_gemm3,
                        hipFuncAttributeMaxDynamicSharedMemorySize, (int)lds_bytes);

    k_prep2    <<<6250, 256, 0, stream>>>(Wself, Wneigh, bself, bneigh, x,
                                          wt, bias, cnt, xb);
    k_scat16   <<<N_EDGES / 256, 256, 0, stream>>>(ei, cnt, col16, spill);
    k_gather16b<<<N_NODES / 4, 256, 0, stream>>>((const unsigned*)xb, cnt,
                                                 col16, spill, out);
    k_gemm3    <<<NT3, 512, lds_bytes, stream>>>(xb, wt, bias, out);
}